// Round 11
// baseline (479.516 us; speedup 1.0000x reference)
//
#include <hip/hip_runtime.h>
#include <math.h>

#define NDIM 128      // feature dim (D == H == 128)

typedef __attribute__((ext_vector_type(8))) short short8;
typedef __attribute__((ext_vector_type(4))) float f32x4;

__device__ __forceinline__ float sigmoidf_(float x){ return 1.0f/(1.0f + __expf(-x)); }

// f32 -> bf16 (round-to-nearest-even)
__device__ __forceinline__ unsigned short f2bf(float f){
  unsigned u = __float_as_uint(f);
  unsigned r = (u + 0x7fffu + ((u >> 16) & 1u)) >> 16;
  return (unsigned short)r;
}
__device__ __forceinline__ float bflo(unsigned u){ return __uint_as_float(u<<16); }
__device__ __forceinline__ float bfhi(unsigned u){ return __uint_as_float(u & 0xffff0000u); }

// stats layout: per layer 8192 floats; feature f: sum at [f*32], sumsq at [f*32+16]
// (64 B line per scalar -> no same-line atomic ping-pong across XCDs)

// ---- init: zero counts/stats/out + W swizzle + graph bounds, ONE dispatch ----
__global__ void init_k(int* __restrict__ counts, float* __restrict__ stats,
                       float* __restrict__ out,
                       const float* __restrict__ W0, const float* __restrict__ W1,
                       const float* __restrict__ W2, unsigned short* __restrict__ Wsw,
                       const int* __restrict__ batch, int* __restrict__ bound,
                       int N, int outsz, int G){
  int i = blockIdx.x*256 + threadIdx.x;
  if(i < N) counts[i] = 0;
  if(i < 3*8192) stats[i] = 0.f;
  if(i < outsz) out[i] = 0.f;
  int d = i - N;
  if(d >= 0 && d < 3*16384){
    int l = d >> 14; int ii = d & 16383;
    const float* W = (l==0) ? W0 : ((l==1) ? W1 : W2);
    int k = ii >> 7, n = ii & 127;
    Wsw[l*16384 + (((k>>3)*128 + n)<<3) + (k&7)] = f2bf(W[k*128+n]);
  }
  int g = i - N - 3*16384;
  if(g >= 0 && g <= G){
    int lo = 0, hi = N;
    while(lo < hi){ int mid = (lo+hi)>>1; if(batch[mid] < g) lo = mid+1; else hi = mid; }
    bound[g] = lo;
  }
}

// ---- CSR pass 1: rank capture (the ONLY atomic pass) ----
__global__ void pass1_k(const int* __restrict__ dst, int* __restrict__ counts,
                        int* __restrict__ rank, int E){
  int e = blockIdx.x*blockDim.x + threadIdx.x;
  if(e < E) rank[e] = atomicAdd(&counts[dst[e]], 1);
}

// ---- scan stage 1: per-chunk inclusive scan + chunk totals ----
__global__ void scan1_k(const int* __restrict__ counts, int* __restrict__ scanned,
                        int* __restrict__ chunksums, int N){
  __shared__ int lds[256];
  int t = threadIdx.x; int idx = blockIdx.x*256 + t;
  int x = (idx < N) ? counts[idx] : 0;
  lds[t] = x; __syncthreads();
  for(int o=1;o<256;o<<=1){
    int v = (t>=o) ? lds[t-o] : 0;
    __syncthreads();
    lds[t] += v;
    __syncthreads();
  }
  if(idx < N) scanned[idx] = lds[t];
  if(t == 255) chunksums[blockIdx.x] = lds[255];
}

// ---- scan stage 2 (fused): chunk-prefix (redundant per block) + row_start + dinv ----
__global__ void scan3_k(const int* __restrict__ scanned, const int* __restrict__ counts,
                        const int* __restrict__ chunksums, int* __restrict__ row_start,
                        float* __restrict__ dinv, int N, int nchunks){
  __shared__ int lds[256];
  int t = threadIdx.x, b = blockIdx.x;
  int x = (t < nchunks) ? chunksums[t] : 0;
  lds[t] = x; __syncthreads();
  for(int o=1;o<256;o<<=1){
    int v = (t>=o) ? lds[t-o] : 0;
    __syncthreads();
    lds[t] += v;
    __syncthreads();
  }
  int base = (b == 0) ? 0 : lds[b-1];     // exclusive prefix for this chunk
  int i = b*256 + t;
  if(i < N){
    row_start[i] = scanned[i] - counts[i] + base;
    dinv[i] = rsqrtf(1.0f + (float)counts[i]);
  }
}

// ---- CSR pass 2: atomic-free placement ----
__global__ void pass2_k(const int* __restrict__ src, const int* __restrict__ dst,
                        const int* __restrict__ rank, const int* __restrict__ row_start,
                        unsigned short* __restrict__ csr, int E){
  int e = blockIdx.x*blockDim.x + threadIdx.x;
  if(e >= E) return;
  csr[row_start[dst[e]] + rank[e]] = (unsigned short)src[e];   // N=50000 < 65536
}

// ---- MFMA GEMM: Bh[N,128](bf16) = dinv[row] * ( bnsig(A)[N,128] @ W[128,128] ) ----
// Layer 0: A = f32 x, no BN (stats==null). Layers 1,2: A = packed-bf16 hC, BN+sigmoid fused.
__global__ __launch_bounds__(256) void gemm_mfma_k(const void* __restrict__ Avoid,
                                                   const unsigned short* __restrict__ Wsw,
                                                   unsigned short* __restrict__ Bh,
                                                   const float* __restrict__ dinv,
                                                   const float* __restrict__ stats,
                                                   const float* __restrict__ gam,
                                                   const float* __restrict__ bet,
                                                   int N){
  __shared__ unsigned short Al[16384];   // 32 KB
  __shared__ unsigned short Wl[16384];   // 32 KB
  __shared__ float scl[NDIM], shl[NDIM], dvl[NDIM];
  int t = threadIdx.x;
  int row0 = blockIdx.x * 128;
  bool bn = (stats != nullptr);

  if(bn && t < NDIM){
    float invN = 1.0f/(float)N;
    float m = stats[t*32]*invN;
    float var = fmaxf(stats[t*32+16]*invN - m*m, 0.f);
    float s = gam[t]*rsqrtf(var + 1e-5f);
    scl[t] = s; shl[t] = bet[t] - m*s;
  }
  if(t < NDIM){
    int r = row0 + t;
    dvl[t] = (r < N) ? dinv[r] : 0.f;
  }
  // stage W: 2048 x 16B coalesced copies
  #pragma unroll
  for(int i=0;i<8;i++){
    int u = t + i*256;
    *(uint4*)&Wl[u<<3] = *(const uint4*)&Wsw[u<<3];
  }
  __syncthreads();   // scl/shl ready before staging uses them

  int o = t & 15, rbase = t >> 4;
  if(bn){
    const unsigned* Ab = (const unsigned*)Avoid;   // packed bf16, N x 64 uints
    #pragma unroll
    for(int it=0; it<8; it++){
      int r = rbase + it*16;
      int grow = row0 + r;
      uint4 pk = {0,0,0,0};
      if(grow < N){
        uint4 pb = *(const uint4*)&Ab[(size_t)grow*64 + o*4];
        float a0=bflo(pb.x), a1=bfhi(pb.x), a2=bflo(pb.y), a3=bfhi(pb.y);
        float a4=bflo(pb.z), a5=bfhi(pb.z), a6=bflo(pb.w), a7=bfhi(pb.w);
        int f = o*8;
        a0 = sigmoidf_(a0*scl[f+0] + shl[f+0]);
        a1 = sigmoidf_(a1*scl[f+1] + shl[f+1]);
        a2 = sigmoidf_(a2*scl[f+2] + shl[f+2]);
        a3 = sigmoidf_(a3*scl[f+3] + shl[f+3]);
        a4 = sigmoidf_(a4*scl[f+4] + shl[f+4]);
        a5 = sigmoidf_(a5*scl[f+5] + shl[f+5]);
        a6 = sigmoidf_(a6*scl[f+6] + shl[f+6]);
        a7 = sigmoidf_(a7*scl[f+7] + shl[f+7]);
        pk.x = (unsigned)f2bf(a0) | ((unsigned)f2bf(a1)<<16);
        pk.y = (unsigned)f2bf(a2) | ((unsigned)f2bf(a3)<<16);
        pk.z = (unsigned)f2bf(a4) | ((unsigned)f2bf(a5)<<16);
        pk.w = (unsigned)f2bf(a6) | ((unsigned)f2bf(a7)<<16);
      }
      *(uint4*)&Al[(o*128 + r)<<3] = pk;
    }
  } else {
    const float* A = (const float*)Avoid;
    #pragma unroll
    for(int it=0; it<8; it++){
      int r = rbase + it*16;
      int grow = row0 + r;
      uint4 pk = {0,0,0,0};
      if(grow < N){
        float4 v0 = *(const float4*)&A[(size_t)grow*NDIM + o*8];
        float4 v1 = *(const float4*)&A[(size_t)grow*NDIM + o*8 + 4];
        pk.x = (unsigned)f2bf(v0.x) | ((unsigned)f2bf(v0.y)<<16);
        pk.y = (unsigned)f2bf(v0.z) | ((unsigned)f2bf(v0.w)<<16);
        pk.z = (unsigned)f2bf(v1.x) | ((unsigned)f2bf(v1.y)<<16);
        pk.w = (unsigned)f2bf(v1.z) | ((unsigned)f2bf(v1.w)<<16);
      }
      *(uint4*)&Al[(o*128 + r)<<3] = pk;
    }
  }
  __syncthreads();

  int wv = t >> 6, lane = t & 63, quad = lane >> 4, l16 = lane & 15;
  int rw = (wv & 1) * 64, cw = (wv >> 1) * 64;
  f32x4 acc[4][4];
  #pragma unroll
  for(int rt=0;rt<4;rt++)
    #pragma unroll
    for(int ct=0;ct<4;ct++) acc[rt][ct] = (f32x4){0.f,0.f,0.f,0.f};

  #pragma unroll
  for(int ks=0; ks<4; ks++){
    short8 a[4], b[4];
    #pragma unroll
    for(int rt=0;rt<4;rt++)
      a[rt] = *(short8*)&Al[(((ks*4+quad)*128) + rw + rt*16 + l16) << 3];
    #pragma unroll
    for(int ct=0;ct<4;ct++)
      b[ct] = *(short8*)&Wl[(((ks*4+quad)*128) + cw + ct*16 + l16) << 3];
    #pragma unroll
    for(int rt=0;rt<4;rt++)
      #pragma unroll
      for(int ct=0;ct<4;ct++)
        acc[rt][ct] = __builtin_amdgcn_mfma_f32_16x16x32_bf16(a[rt], b[ct], acc[rt][ct], 0, 0, 0);
  }

  // epilogue: C/D layout col=lane&15, row=quad*4+reg; pre-scale by dinv[row]
  #pragma unroll
  for(int rt=0;rt<4;rt++){
    int lr = rw + rt*16 + quad*4;
    int gr = row0 + lr;
    #pragma unroll
    for(int reg=0;reg<4;reg++){
      float dv = dvl[lr + reg];
      if(gr + reg < N){
        #pragma unroll
        for(int ct=0;ct<4;ct++){
          int col = cw + ct*16 + l16;
          Bh[(size_t)(gr+reg)*NDIM + col] = f2bf(acc[rt][ct][reg]*dv);
        }
      }
    }
  }
}

// ---- CSR gather aggregation + fused BN stats (grid-stride, register stats) ----
// hCb[i] (bf16x2) = dinv[i]*( sum_e hbs[src] + hbs[i] ) + bias
// Each wave owns features {2*lane, 2*lane+1}; stats accumulate in registers across
// all rows the wave processes; one LDS reduce + 256 padded-line atomics per block.
#define AGG_GRID 1024
__global__ __launch_bounds__(256) void agg_k(const unsigned int* __restrict__ hb,
                      const float* __restrict__ dinv,
                      const int* __restrict__ row_start, const int* __restrict__ counts,
                      const unsigned short* __restrict__ csr,
                      const float* __restrict__ bias, unsigned int* __restrict__ hCb,
                      float* __restrict__ stats, int N){
  __shared__ float se[256], so[256], qe[256], qo[256];
  int t = threadIdx.x;
  int lane = t & 63, w = t >> 6;
  float2 bv = *(const float2*)&bias[lane*2];
  float sx = 0.f, sy = 0.f, qx = 0.f, qy = 0.f;

  for(int i = blockIdx.x*4 + w; i < N; i += gridDim.x*4){
    int rs = row_start[i], re = rs + counts[i];
    float ax = 0.f, ay = 0.f;
    int j = rs;
    for(; j+7 < re; j += 8){           // 8 row-gathers in flight per wave
      int s0=csr[j],   s1=csr[j+1], s2=csr[j+2], s3=csr[j+3];
      int s4=csr[j+4], s5=csr[j+5], s6=csr[j+6], s7=csr[j+7];
      unsigned u0 = hb[(size_t)s0*64 + lane];
      unsigned u1 = hb[(size_t)s1*64 + lane];
      unsigned u2 = hb[(size_t)s2*64 + lane];
      unsigned u3 = hb[(size_t)s3*64 + lane];
      unsigned u4 = hb[(size_t)s4*64 + lane];
      unsigned u5 = hb[(size_t)s5*64 + lane];
      unsigned u6 = hb[(size_t)s6*64 + lane];
      unsigned u7 = hb[(size_t)s7*64 + lane];
      ax += bflo(u0)+bflo(u1)+bflo(u2)+bflo(u3)+bflo(u4)+bflo(u5)+bflo(u6)+bflo(u7);
      ay += bfhi(u0)+bfhi(u1)+bfhi(u2)+bfhi(u3)+bfhi(u4)+bfhi(u5)+bfhi(u6)+bfhi(u7);
    }
    for(; j < re; j++){
      unsigned u0 = hb[(size_t)csr[j]*64 + lane];
      ax += bflo(u0);
      ay += bfhi(u0);
    }
    float di = dinv[i];
    unsigned su = hb[(size_t)i*64 + lane];
    float ox = di*(ax + bflo(su)) + bv.x;
    float oy = di*(ay + bfhi(su)) + bv.y;
    hCb[(size_t)i*64 + lane] = (unsigned)f2bf(ox) | ((unsigned)f2bf(oy)<<16);
    sx += ox; qx += ox*ox;
    sy += oy; qy += oy*oy;
  }

  se[t] = sx; so[t] = sy; qe[t] = qx; qo[t] = qy;
  __syncthreads();
  if(t < 64){
    float s = se[t]+se[t+64]+se[t+128]+se[t+192];
    float q = qe[t]+qe[t+64]+qe[t+128]+qe[t+192];
    atomicAdd(&stats[(2*t)*32],      s);
    atomicAdd(&stats[(2*t)*32 + 16], q);
  } else if(t < 128){
    int l = t - 64;
    float s = so[l]+so[l+64]+so[l+128]+so[l+192];
    float q = qo[l]+qo[l+64]+qo[l+128]+qo[l+192];
    atomicAdd(&stats[(2*l+1)*32],      s);
    atomicAdd(&stats[(2*l+1)*32 + 16], q);
  }
}

// ---- pooling phase 1: segment-sum of sigmoid(v*scale+shift); finalize fused ----
#define PCH 128
__global__ __launch_bounds__(256) void pool_k(const unsigned* __restrict__ hb,
                                              const int* __restrict__ batch,
                                              const float* __restrict__ stats,
                                              const float* __restrict__ gam,
                                              const float* __restrict__ bet,
                                              float* __restrict__ out, int N){
  __shared__ float scl[NDIM], shl[NDIM];
  int t = threadIdx.x;
  if(t < NDIM){
    float invN = 1.0f/(float)N;
    float m = stats[t*32]*invN;
    float var = fmaxf(stats[t*32+16]*invN - m*m, 0.f);
    float s = gam[t]*rsqrtf(var + 1e-5f);
    scl[t] = s; shl[t] = bet[t] - m*s;
  }
  __syncthreads();
  int f = t & 127, half = t >> 7;
  int r0 = blockIdx.x*PCH + half;
  int r1 = min(N, blockIdx.x*PCH + PCH);
  float sc = scl[f], sh = shl[f];
  float acc = 0.f; int cur = -1;
  for(int r = r0; r < r1; r += 2){
    int g = batch[r];
    if(g != cur){
      if(cur >= 0) atomicAdd(&out[cur*NDIM + f], acc);
      acc = 0.f; cur = g;
    }
    unsigned u = hb[(size_t)r*64 + (f>>1)];
    float v = (f&1) ? bfhi(u) : bflo(u);
    acc += sigmoidf_(v*sc + sh);
  }
  if(cur >= 0) atomicAdd(&out[cur*NDIM + f], acc);
}

// ---- pooling phase 2: divide by graph size ----
__global__ void div_k(float* __restrict__ out, const int* __restrict__ bound){
  int g = blockIdx.x, f = threadIdx.x;
  float cnt = (float)(bound[g+1] - bound[g]);
  out[g*NDIM + f] /= fmaxf(cnt, 1.0f);
}

extern "C" void kernel_launch(void* const* d_in, const int* in_sizes, int n_in,
                              void* d_out, int out_size, void* d_ws, size_t ws_size,
                              hipStream_t stream){
  const float* x     = (const float*)d_in[0];
  const int*   ei    = (const int*)d_in[1];
  const int*   batch = (const int*)d_in[3];
  const float* W [3] = {(const float*)d_in[4], (const float*)d_in[6], (const float*)d_in[8]};
  const float* bi[3] = {(const float*)d_in[5], (const float*)d_in[7], (const float*)d_in[9]};
  const float* gg[3] = {(const float*)d_in[10], (const float*)d_in[12], (const float*)d_in[14]};
  const float* bb[3] = {(const float*)d_in[11], (const float*)d_in[13], (const float*)d_in[15]};

  int N = in_sizes[0] / NDIM;
  int E = in_sizes[1] / 2;
  int G = out_size / NDIM;
  const int* src = ei;
  const int* dst = ei + E;

  // workspace bump allocator (256 B aligned)
  char* p = (char*)d_ws;
  auto alloc = [&](size_t bytes)->void*{
    void* r = (void*)p; p += (bytes + 255) & ~(size_t)255; return r;
  };
  unsigned short* hB  = (unsigned short*)alloc((size_t)N*NDIM*2);   // bf16, pre-scaled by dinv
  unsigned*       hCb = (unsigned*)      alloc((size_t)N*64*4);     // packed bf16x2
  unsigned short* Wsw = (unsigned short*)alloc(3*16384*2);
  int*   counts    = (int*)  alloc((size_t)N*4);
  int*   rank      = (int*)  alloc((size_t)E*4);
  int*   scanned   = (int*)  alloc((size_t)N*4);
  int*   chunksums = (int*)  alloc(256*4);
  int*   row_start = (int*)  alloc((size_t)N*4);
  float* dinv      = (float*)alloc((size_t)N*4);
  unsigned short* csr = (unsigned short*)alloc((size_t)E*2);
  float* stats     = (float*)alloc((size_t)3*8192*4);   // line-padded stats, 3 layers
  int*   bound     = (int*)  alloc(256*4);

  int initmax = N + 3*16384 + G + 1;
  init_k<<<(initmax+255)/256, 256, 0, stream>>>(counts, stats, (float*)d_out,
                                                W[0], W[1], W[2], Wsw, batch, bound,
                                                N, out_size, G);

  pass1_k<<<(E+255)/256, 256, 0, stream>>>(dst, counts, rank, E);

  int nchunks = (N+255)/256;     // 196 <= 256
  scan1_k<<<nchunks, 256, 0, stream>>>(counts, scanned, chunksums, N);
  scan3_k<<<nchunks, 256, 0, stream>>>(scanned, counts, chunksums, row_start, dinv, N, nchunks);
  pass2_k<<<(E+255)/256, 256, 0, stream>>>(src, dst, rank, row_start, csr, E);

  const void* hin = (const void*)x;
  for(int l=0; l<3; l++){
    const float* st = (l == 0) ? nullptr : (stats + (l-1)*8192);
    const float* gm = (l == 0) ? nullptr : gg[l-1];
    const float* be = (l == 0) ? nullptr : bb[l-1];
    gemm_mfma_k<<<(N+127)/128, 256, 0, stream>>>(hin, Wsw + l*16384, hB, dinv,
                                                 st, gm, be, N);
    agg_k<<<AGG_GRID, 256, 0, stream>>>((const unsigned int*)hB, dinv, row_start, counts,
                                        csr, bi[l], hCb, stats + l*8192, N);
    hin = (const void*)hCb;
  }

  pool_k<<<(N+PCH-1)/PCH, 256, 0, stream>>>(hCb, batch, stats + 2*8192,
                                            gg[2], bb[2], (float*)d_out, N);
  div_k<<<G, 128, 0, stream>>>((float*)d_out, bound);
}

// Round 12
// 438.138 us; speedup vs baseline: 1.0944x; 1.0944x over previous
//
#include <hip/hip_runtime.h>
#include <math.h>

#define NDIM 128      // feature dim (D == H == 128)

typedef __attribute__((ext_vector_type(8))) short short8;
typedef __attribute__((ext_vector_type(4))) float f32x4;

__device__ __forceinline__ float sigmoidf_(float x){ return 1.0f/(1.0f + __expf(-x)); }

// f32 -> bf16 (round-to-nearest-even)
__device__ __forceinline__ unsigned short f2bf(float f){
  unsigned u = __float_as_uint(f);
  unsigned r = (u + 0x7fffu + ((u >> 16) & 1u)) >> 16;
  return (unsigned short)r;
}
__device__ __forceinline__ float bflo(unsigned u){ return __uint_as_float(u<<16); }
__device__ __forceinline__ float bfhi(unsigned u){ return __uint_as_float(u & 0xffff0000u); }

// ---- OCP fp8 e4m3fn encode/decode (native cvt when available, bit-exact fallback) ----
__device__ __forceinline__ unsigned char enc_fp8(float f){
#if __has_builtin(__builtin_amdgcn_cvt_pk_fp8_f32)
  int p = __builtin_amdgcn_cvt_pk_fp8_f32(f, 0.f, 0, false);
  return (unsigned char)(p & 0xff);
#else
  unsigned u = __float_as_uint(f);
  unsigned s = (u >> 24) & 0x80u;
  unsigned a = u & 0x7fffffffu;
  if(a >= 0x43e00000u) return (unsigned char)(s | 0x7eu);   // clamp to +-448
  if(a < 0x3c800000u){                                      // |f| < 2^-6 -> subnormal (m * 2^-9)
    unsigned m3 = (unsigned)__float2int_rn(__uint_as_float(a) * 512.0f);
    return (unsigned char)(s | m3);                         // m3==8 carries to min normal
  }
  unsigned keep = a >> 20;
  unsigned rnd = (a >> 19) & 1u;
  unsigned sticky = (a & 0x7ffffu) ? 1u : 0u;
  keep += rnd & ((keep & 1u) | sticky);                     // RNE
  unsigned e8 = (keep >> 3) - 120u;
  if(e8 >= 16u) return (unsigned char)(s | 0x7eu);
  return (unsigned char)(s | (e8 << 3) | (keep & 7u));
#endif
}

__device__ __forceinline__ float fp8_dec_(unsigned b){      // b = one fp8 byte
  unsigned m7 = b & 0x7fu;
  float mag = __uint_as_float((m7 << 20) + 0x3c000000u);    // (1+m/8)*2^(e-7)
  if((b & 0x78u) == 0) mag = 2.0f*mag - 0.015625f;          // denormal fixup -> m*2^-9
  return (b & 0x80u) ? -mag : mag;
}
__device__ __forceinline__ float dec_lo(unsigned h){        // byte 0 of ushort
#if __has_builtin(__builtin_amdgcn_cvt_f32_fp8)
  return __builtin_amdgcn_cvt_f32_fp8((int)h, 0);
#else
  return fp8_dec_(h & 0xffu);
#endif
}
__device__ __forceinline__ float dec_hi(unsigned h){        // byte 1 of ushort
#if __has_builtin(__builtin_amdgcn_cvt_f32_fp8)
  return __builtin_amdgcn_cvt_f32_fp8((int)h, 1);
#else
  return fp8_dec_((h >> 8) & 0xffu);
#endif
}

// ---- CSR pass 1: rank capture (the ONLY atomic pass) ----
__global__ void pass1_k(const int* __restrict__ dst, int* __restrict__ counts,
                        int* __restrict__ rank, int E){
  int e = blockIdx.x*blockDim.x + threadIdx.x;
  if(e < E) rank[e] = atomicAdd(&counts[dst[e]], 1);
}

// ---- scan stage 1: per-chunk inclusive scan + chunk totals ----
__global__ void scan1_k(const int* __restrict__ counts, int* __restrict__ scanned,
                        int* __restrict__ chunksums, int N){
  __shared__ int lds[256];
  int t = threadIdx.x; int idx = blockIdx.x*256 + t;
  int x = (idx < N) ? counts[idx] : 0;
  lds[t] = x; __syncthreads();
  for(int o=1;o<256;o<<=1){
    int v = (t>=o) ? lds[t-o] : 0;
    __syncthreads();
    lds[t] += v;
    __syncthreads();
  }
  if(idx < N) scanned[idx] = lds[t];
  if(t == 255) chunksums[blockIdx.x] = lds[255];
}

__global__ void scan2_k(int* __restrict__ chunksums, int nchunks){
  __shared__ int lds[256];
  int t = threadIdx.x;
  int x = (t < nchunks) ? chunksums[t] : 0;
  lds[t] = x; __syncthreads();
  for(int o=1;o<256;o<<=1){
    int v = (t>=o) ? lds[t-o] : 0;
    __syncthreads();
    lds[t] += v;
    __syncthreads();
  }
  if(t < nchunks) chunksums[t] = lds[t] - x;   // exclusive
}

// scan3 + dinv fused (both only need counts)
__global__ void scan3_k(const int* __restrict__ scanned, const int* __restrict__ counts,
                        const int* __restrict__ chunksums, int* __restrict__ row_start,
                        float* __restrict__ dinv, int N){
  int i = blockIdx.x*blockDim.x + threadIdx.x;
  if(i < N){
    row_start[i] = scanned[i] - counts[i] + chunksums[i>>8];
    dinv[i] = rsqrtf(1.0f + (float)counts[i]);
  }
}

// ---- CSR pass 2: atomic-free placement ----
__global__ void pass2_k(const int* __restrict__ src, const int* __restrict__ dst,
                        const int* __restrict__ rank, const int* __restrict__ row_start,
                        unsigned short* __restrict__ csr, int E){
  int e = blockIdx.x*blockDim.x + threadIdx.x;
  if(e >= E) return;
  csr[row_start[dst[e]] + rank[e]] = (unsigned short)src[e];   // N=50000 < 65536
}

// ---- W prep (bf16 swizzle, 3 layers) + graph bounds (tail threads) ----
__global__ void wprep_k(const float* __restrict__ W0, const float* __restrict__ W1,
                        const float* __restrict__ W2, unsigned short* __restrict__ Wsw,
                        const int* __restrict__ batch, int* __restrict__ bound,
                        int N, int G){
  int t = blockIdx.x*256 + threadIdx.x;
  if(t < 3*16384){
    int l = t >> 14; int i = t & 16383;
    const float* W = (l==0) ? W0 : ((l==1) ? W1 : W2);
    int k = i >> 7, n = i & 127;
    Wsw[l*16384 + (((k>>3)*128 + n)<<3) + (k&7)] = f2bf(W[k*128+n]);
  } else {
    int g = t - 3*16384;
    if(g <= G){
      int lo = 0, hi = N;
      while(lo < hi){ int mid = (lo+hi)>>1; if(batch[mid] < g) lo = mid+1; else hi = mid; }
      bound[g] = lo;
    }
  }
}

// ---- MFMA GEMM: Bh8[N,128](fp8) = dinv[row] * ( bnsig(A)[N,128] @ W[128,128] ) ----
// Layer 0: A = f32 x, no BN. Layers 1,2: A = packed-bf16 hC, BN+sigmoid fused.
__global__ __launch_bounds__(256) void gemm_mfma_k(const void* __restrict__ Avoid,
                                                   const unsigned short* __restrict__ Wsw,
                                                   unsigned char* __restrict__ Bh8,
                                                   const float* __restrict__ dinv,
                                                   const float* __restrict__ sums,
                                                   const float* __restrict__ sumsq,
                                                   const float* __restrict__ gam,
                                                   const float* __restrict__ bet,
                                                   int N){
  __shared__ unsigned short Al[16384];   // 32 KB
  __shared__ unsigned short Wl[16384];   // 32 KB
  __shared__ float scl[NDIM], shl[NDIM], dvl[NDIM];
  int t = threadIdx.x;
  int row0 = blockIdx.x * 128;
  bool bn = (sums != nullptr);

  if(bn && t < NDIM){
    float invN = 1.0f/(float)N;
    float m = sums[t]*invN;
    float var = fmaxf(sumsq[t]*invN - m*m, 0.f);
    float s = gam[t]*rsqrtf(var + 1e-5f);
    scl[t] = s; shl[t] = bet[t] - m*s;
  }
  if(t < NDIM){
    int r = row0 + t;
    dvl[t] = (r < N) ? dinv[r] : 0.f;
  }
  // stage W: 2048 x 16B coalesced copies
  #pragma unroll
  for(int i=0;i<8;i++){
    int u = t + i*256;
    *(uint4*)&Wl[u<<3] = *(const uint4*)&Wsw[u<<3];
  }
  __syncthreads();   // scl/shl ready before staging uses them

  int o = t & 15, rbase = t >> 4;
  if(bn){
    const unsigned* Ab = (const unsigned*)Avoid;   // packed bf16, N x 64 uints
    #pragma unroll
    for(int it=0; it<8; it++){
      int r = rbase + it*16;
      int grow = row0 + r;
      uint4 pk = {0,0,0,0};
      if(grow < N){
        uint4 pb = *(const uint4*)&Ab[(size_t)grow*64 + o*4];
        float a0=bflo(pb.x), a1=bfhi(pb.x), a2=bflo(pb.y), a3=bfhi(pb.y);
        float a4=bflo(pb.z), a5=bfhi(pb.z), a6=bflo(pb.w), a7=bfhi(pb.w);
        int f = o*8;
        a0 = sigmoidf_(a0*scl[f+0] + shl[f+0]);
        a1 = sigmoidf_(a1*scl[f+1] + shl[f+1]);
        a2 = sigmoidf_(a2*scl[f+2] + shl[f+2]);
        a3 = sigmoidf_(a3*scl[f+3] + shl[f+3]);
        a4 = sigmoidf_(a4*scl[f+4] + shl[f+4]);
        a5 = sigmoidf_(a5*scl[f+5] + shl[f+5]);
        a6 = sigmoidf_(a6*scl[f+6] + shl[f+6]);
        a7 = sigmoidf_(a7*scl[f+7] + shl[f+7]);
        pk.x = (unsigned)f2bf(a0) | ((unsigned)f2bf(a1)<<16);
        pk.y = (unsigned)f2bf(a2) | ((unsigned)f2bf(a3)<<16);
        pk.z = (unsigned)f2bf(a4) | ((unsigned)f2bf(a5)<<16);
        pk.w = (unsigned)f2bf(a6) | ((unsigned)f2bf(a7)<<16);
      }
      *(uint4*)&Al[(o*128 + r)<<3] = pk;
    }
  } else {
    const float* A = (const float*)Avoid;
    #pragma unroll
    for(int it=0; it<8; it++){
      int r = rbase + it*16;
      int grow = row0 + r;
      uint4 pk = {0,0,0,0};
      if(grow < N){
        float4 v0 = *(const float4*)&A[(size_t)grow*NDIM + o*8];
        float4 v1 = *(const float4*)&A[(size_t)grow*NDIM + o*8 + 4];
        pk.x = (unsigned)f2bf(v0.x) | ((unsigned)f2bf(v0.y)<<16);
        pk.y = (unsigned)f2bf(v0.z) | ((unsigned)f2bf(v0.w)<<16);
        pk.z = (unsigned)f2bf(v1.x) | ((unsigned)f2bf(v1.y)<<16);
        pk.w = (unsigned)f2bf(v1.z) | ((unsigned)f2bf(v1.w)<<16);
      }
      *(uint4*)&Al[(o*128 + r)<<3] = pk;
    }
  }
  __syncthreads();

  int wv = t >> 6, lane = t & 63, quad = lane >> 4, l16 = lane & 15;
  int rw = (wv & 1) * 64, cw = (wv >> 1) * 64;
  f32x4 acc[4][4];
  #pragma unroll
  for(int rt=0;rt<4;rt++)
    #pragma unroll
    for(int ct=0;ct<4;ct++) acc[rt][ct] = (f32x4){0.f,0.f,0.f,0.f};

  #pragma unroll
  for(int ks=0; ks<4; ks++){
    short8 a[4], b[4];
    #pragma unroll
    for(int rt=0;rt<4;rt++)
      a[rt] = *(short8*)&Al[(((ks*4+quad)*128) + rw + rt*16 + l16) << 3];
    #pragma unroll
    for(int ct=0;ct<4;ct++)
      b[ct] = *(short8*)&Wl[(((ks*4+quad)*128) + cw + ct*16 + l16) << 3];
    #pragma unroll
    for(int rt=0;rt<4;rt++)
      #pragma unroll
      for(int ct=0;ct<4;ct++)
        acc[rt][ct] = __builtin_amdgcn_mfma_f32_16x16x32_bf16(a[rt], b[ct], acc[rt][ct], 0, 0, 0);
  }

  // epilogue: C/D layout col=lane&15, row=quad*4+reg; pre-scale by dinv[row], fp8 store
  #pragma unroll
  for(int rt=0;rt<4;rt++){
    int lr = rw + rt*16 + quad*4;
    int gr = row0 + lr;
    #pragma unroll
    for(int reg=0;reg<4;reg++){
      float dv = dvl[lr + reg];
      if(gr + reg < N){
        #pragma unroll
        for(int ct=0;ct<4;ct++){
          int col = cw + ct*16 + l16;
          Bh8[(size_t)(gr+reg)*NDIM + col] = enc_fp8(acc[rt][ct][reg]*dv);
        }
      }
    }
  }
}

// ---- CSR gather aggregation: one wave per dst row; hb8 rows fp8, pre-scaled by dinv[src] ----
// hCb[i] (bf16x2) = dinv[i]*( sum_e hb8[src] + hb8[i] ) + bias
__global__ void agg_k(const unsigned short* __restrict__ hb8,   // fp8x2 per lane
                      const float* __restrict__ dinv,
                      const int* __restrict__ row_start, const int* __restrict__ counts,
                      const unsigned short* __restrict__ csr,
                      const float* __restrict__ bias, unsigned int* __restrict__ hCb, int N){
  int i = blockIdx.x;
  if(i >= N) return;
  int lane = threadIdx.x;            // 64 lanes, lane = feature pair (ushort = 2 fp8)
  int rs = row_start[i], re = rs + counts[i];
  float ax = 0.f, ay = 0.f;
  int j = rs;
  for(; j+7 < re; j += 8){           // 8 row-gathers in flight
    int s0=csr[j],   s1=csr[j+1], s2=csr[j+2], s3=csr[j+3];
    int s4=csr[j+4], s5=csr[j+5], s6=csr[j+6], s7=csr[j+7];
    unsigned u0 = hb8[(size_t)s0*64 + lane];
    unsigned u1 = hb8[(size_t)s1*64 + lane];
    unsigned u2 = hb8[(size_t)s2*64 + lane];
    unsigned u3 = hb8[(size_t)s3*64 + lane];
    unsigned u4 = hb8[(size_t)s4*64 + lane];
    unsigned u5 = hb8[(size_t)s5*64 + lane];
    unsigned u6 = hb8[(size_t)s6*64 + lane];
    unsigned u7 = hb8[(size_t)s7*64 + lane];
    ax += dec_lo(u0)+dec_lo(u1)+dec_lo(u2)+dec_lo(u3)
        + dec_lo(u4)+dec_lo(u5)+dec_lo(u6)+dec_lo(u7);
    ay += dec_hi(u0)+dec_hi(u1)+dec_hi(u2)+dec_hi(u3)
        + dec_hi(u4)+dec_hi(u5)+dec_hi(u6)+dec_hi(u7);
  }
  for(; j < re; j++){
    unsigned u0 = hb8[(size_t)csr[j]*64 + lane];
    ax += dec_lo(u0);
    ay += dec_hi(u0);
  }
  float di = dinv[i];
  unsigned su = hb8[(size_t)i*64 + lane];
  float2 bv = *(const float2*)&bias[lane*2];
  float ox = di*(ax + dec_lo(su)) + bv.x;
  float oy = di*(ay + dec_hi(su)) + bv.y;
  hCb[(size_t)i*64 + lane] = (unsigned)f2bf(ox) | ((unsigned)f2bf(oy)<<16);
}

// ---- BN column stats over packed-bf16 hC ----
__global__ void stats_k(const unsigned* __restrict__ hb, float* __restrict__ sums,
                        float* __restrict__ sumsq, int N){
  __shared__ float ls[256], lq[256];
  int t = threadIdx.x;
  int f = t & 127, half = t >> 7;
  int rowsPerBlock = (N + gridDim.x - 1)/gridDim.x;
  int r0 = blockIdx.x * rowsPerBlock;
  int r1 = min(N, r0 + rowsPerBlock);
  float s=0.f, q=0.f;
  for(int r=r0+half; r<r1; r+=2){
    unsigned u = hb[(size_t)r*64 + (f>>1)];
    float v = (f&1) ? bfhi(u) : bflo(u);
    s += v; q += v*v;
  }
  ls[t]=s; lq[t]=q; __syncthreads();
  if(t < 128){
    s = ls[t] + ls[t+128];
    q = lq[t] + lq[t+128];
    atomicAdd(&sums[f], s);
    atomicAdd(&sumsq[f], q);
  }
}

// ---- pooling phase 1: segment-sum of sigmoid(v*scale+shift); finalize fused ----
#define PCH 128
__global__ __launch_bounds__(256) void pool_k(const unsigned* __restrict__ hb,
                                              const int* __restrict__ batch,
                                              const float* __restrict__ sums,
                                              const float* __restrict__ sumsq,
                                              const float* __restrict__ gam,
                                              const float* __restrict__ bet,
                                              float* __restrict__ out, int N){
  __shared__ float scl[NDIM], shl[NDIM];
  int t = threadIdx.x;
  if(t < NDIM){
    float invN = 1.0f/(float)N;
    float m = sums[t]*invN;
    float var = fmaxf(sumsq[t]*invN - m*m, 0.f);
    float s = gam[t]*rsqrtf(var + 1e-5f);
    scl[t] = s; shl[t] = bet[t] - m*s;
  }
  __syncthreads();
  int f = t & 127, half = t >> 7;
  int r0 = blockIdx.x*PCH + half;
  int r1 = min(N, blockIdx.x*PCH + PCH);
  float sc = scl[f], sh = shl[f];
  float acc = 0.f; int cur = -1;
  for(int r = r0; r < r1; r += 2){
    int g = batch[r];
    if(g != cur){
      if(cur >= 0) atomicAdd(&out[cur*NDIM + f], acc);
      acc = 0.f; cur = g;
    }
    unsigned u = hb[(size_t)r*64 + (f>>1)];
    float v = (f&1) ? bfhi(u) : bflo(u);
    acc += sigmoidf_(v*sc + sh);
  }
  if(cur >= 0) atomicAdd(&out[cur*NDIM + f], acc);
}

// ---- pooling phase 2: divide by graph size ----
__global__ void div_k(float* __restrict__ out, const int* __restrict__ bound){
  int g = blockIdx.x, f = threadIdx.x;
  float cnt = (float)(bound[g+1] - bound[g]);
  out[g*NDIM + f] /= fmaxf(cnt, 1.0f);
}

extern "C" void kernel_launch(void* const* d_in, const int* in_sizes, int n_in,
                              void* d_out, int out_size, void* d_ws, size_t ws_size,
                              hipStream_t stream){
  const float* x     = (const float*)d_in[0];
  const int*   ei    = (const int*)d_in[1];
  const int*   batch = (const int*)d_in[3];
  const float* W [3] = {(const float*)d_in[4], (const float*)d_in[6], (const float*)d_in[8]};
  const float* bi[3] = {(const float*)d_in[5], (const float*)d_in[7], (const float*)d_in[9]};
  const float* gg[3] = {(const float*)d_in[10], (const float*)d_in[12], (const float*)d_in[14]};
  const float* bb[3] = {(const float*)d_in[11], (const float*)d_in[13], (const float*)d_in[15]};

  int N = in_sizes[0] / NDIM;
  int E = in_sizes[1] / 2;
  int G = out_size / NDIM;
  const int* src = ei;
  const int* dst = ei + E;

  // workspace bump allocator (256 B aligned)
  char* p = (char*)d_ws;
  auto alloc = [&](size_t bytes)->void*{
    void* r = (void*)p; p += (bytes + 255) & ~(size_t)255; return r;
  };
  unsigned char*  hB8 = (unsigned char*) alloc((size_t)N*NDIM);     // fp8, pre-scaled by dinv
  unsigned*       hCb = (unsigned*)      alloc((size_t)N*64*4);     // packed bf16x2
  unsigned short* Wsw = (unsigned short*)alloc(3*16384*2);
  int*   counts    = (int*)  alloc((size_t)N*4);
  int*   rank      = (int*)  alloc((size_t)E*4);
  int*   scanned   = (int*)  alloc((size_t)N*4);
  int*   chunksums = (int*)  alloc(256*4);
  int*   row_start = (int*)  alloc((size_t)N*4);
  float* dinv      = (float*)alloc((size_t)N*4);
  unsigned short* csr = (unsigned short*)alloc((size_t)E*2);
  float* sums      = (float*)alloc(2*3*128*4);      // sums[3][128] + sumsq[3][128]
  float* sumsq     = sums + 3*128;
  int*   bound     = (int*)  alloc(256*4);

  hipMemsetAsync(counts, 0, (size_t)N*4, stream);
  hipMemsetAsync(sums,  0, 2*3*128*4, stream);
  hipMemsetAsync(d_out, 0, (size_t)out_size*4, stream);

  pass1_k<<<(E+255)/256, 256, 0, stream>>>(dst, counts, rank, E);

  int nchunks = (N+255)/256;     // 196 <= 256
  scan1_k<<<nchunks, 256, 0, stream>>>(counts, scanned, chunksums, N);
  scan2_k<<<1, 256, 0, stream>>>(chunksums, nchunks);
  scan3_k<<<(N+255)/256, 256, 0, stream>>>(scanned, counts, chunksums, row_start, dinv, N);
  pass2_k<<<(E+255)/256, 256, 0, stream>>>(src, dst, rank, row_start, csr, E);
  wprep_k<<<(3*16384+256+255)/256, 256, 0, stream>>>(W[0], W[1], W[2], Wsw, batch, bound, N, G);

  const void* hin = (const void*)x;
  for(int l=0; l<3; l++){
    const float* sm = (l == 0) ? nullptr : (sums  + (l-1)*128);
    const float* sq = (l == 0) ? nullptr : (sumsq + (l-1)*128);
    const float* gm = (l == 0) ? nullptr : gg[l-1];
    const float* be = (l == 0) ? nullptr : bb[l-1];
    gemm_mfma_k<<<(N+127)/128, 256, 0, stream>>>(hin, Wsw + l*16384, hB8, dinv,
                                                 sm, sq, gm, be, N);
    agg_k<<<N, 64, 0, stream>>>((const unsigned short*)hB8, dinv, row_start, counts,
                                csr, bi[l], hCb, N);
    stats_k<<<400, 256, 0, stream>>>(hCb, sums + l*128, sumsq + l*128, N);
    hin = (const void*)hCb;
  }

  pool_k<<<(N+PCH-1)/PCH, 256, 0, stream>>>(hCb, batch, sums + 2*128, sumsq + 2*128,
                                            gg[2], bb[2], (float*)d_out, N);
  div_k<<<G, 128, 0, stream>>>((float*)d_out, bound);
}

// Round 13
// 423.892 us; speedup vs baseline: 1.1312x; 1.0336x over previous
//
#include <hip/hip_runtime.h>
#include <math.h>

#define NDIM 128      // feature dim (D == H == 128)

typedef __attribute__((ext_vector_type(8))) short short8;
typedef __attribute__((ext_vector_type(4))) float f32x4;

__device__ __forceinline__ float sigmoidf_(float x){ return 1.0f/(1.0f + __expf(-x)); }

// f32 -> bf16 (round-to-nearest-even)
__device__ __forceinline__ unsigned short f2bf(float f){
  unsigned u = __float_as_uint(f);
  unsigned r = (u + 0x7fffu + ((u >> 16) & 1u)) >> 16;
  return (unsigned short)r;
}
__device__ __forceinline__ float bflo(unsigned u){ return __uint_as_float(u<<16); }
__device__ __forceinline__ float bfhi(unsigned u){ return __uint_as_float(u & 0xffff0000u); }

// ---- OCP fp8 e4m3fn encode/decode (native cvt when available, bit-exact fallback) ----
__device__ __forceinline__ unsigned char enc_fp8(float f){
#if __has_builtin(__builtin_amdgcn_cvt_pk_fp8_f32)
  int p = __builtin_amdgcn_cvt_pk_fp8_f32(f, 0.f, 0, false);
  return (unsigned char)(p & 0xff);
#else
  unsigned u = __float_as_uint(f);
  unsigned s = (u >> 24) & 0x80u;
  unsigned a = u & 0x7fffffffu;
  if(a >= 0x43e00000u) return (unsigned char)(s | 0x7eu);   // clamp to +-448
  if(a < 0x3c800000u){                                      // |f| < 2^-6 -> subnormal (m * 2^-9)
    unsigned m3 = (unsigned)__float2int_rn(__uint_as_float(a) * 512.0f);
    return (unsigned char)(s | m3);                         // m3==8 carries to min normal
  }
  unsigned keep = a >> 20;
  unsigned rnd = (a >> 19) & 1u;
  unsigned sticky = (a & 0x7ffffu) ? 1u : 0u;
  keep += rnd & ((keep & 1u) | sticky);                     // RNE
  unsigned e8 = (keep >> 3) - 120u;
  if(e8 >= 16u) return (unsigned char)(s | 0x7eu);
  return (unsigned char)(s | (e8 << 3) | (keep & 7u));
#endif
}

__device__ __forceinline__ float fp8_dec_(unsigned b){      // b = one fp8 byte
  unsigned m7 = b & 0x7fu;
  float mag = __uint_as_float((m7 << 20) + 0x3c000000u);    // (1+m/8)*2^(e-7)
  if((b & 0x78u) == 0) mag = 2.0f*mag - 0.015625f;          // denormal fixup -> m*2^-9
  return (b & 0x80u) ? -mag : mag;
}
__device__ __forceinline__ float dec_lo(unsigned h){        // byte 0 of ushort
#if __has_builtin(__builtin_amdgcn_cvt_f32_fp8)
  return __builtin_amdgcn_cvt_f32_fp8((int)h, 0);
#else
  return fp8_dec_(h & 0xffu);
#endif
}
__device__ __forceinline__ float dec_hi(unsigned h){        // byte 1 of ushort
#if __has_builtin(__builtin_amdgcn_cvt_f32_fp8)
  return __builtin_amdgcn_cvt_f32_fp8((int)h, 1);
#else
  return fp8_dec_((h >> 8) & 0xffu);
#endif
}

// ---- CSR pass 1: rank capture (the ONLY atomic pass) ----
__global__ void pass1_k(const int* __restrict__ dst, int* __restrict__ counts,
                        int* __restrict__ rank, int E){
  int e = blockIdx.x*blockDim.x + threadIdx.x;
  if(e < E) rank[e] = atomicAdd(&counts[dst[e]], 1);
}

// ---- scan stage 1: per-chunk inclusive scan + chunk totals ----
__global__ void scan1_k(const int* __restrict__ counts, int* __restrict__ scanned,
                        int* __restrict__ chunksums, int N){
  __shared__ int lds[256];
  int t = threadIdx.x; int idx = blockIdx.x*256 + t;
  int x = (idx < N) ? counts[idx] : 0;
  lds[t] = x; __syncthreads();
  for(int o=1;o<256;o<<=1){
    int v = (t>=o) ? lds[t-o] : 0;
    __syncthreads();
    lds[t] += v;
    __syncthreads();
  }
  if(idx < N) scanned[idx] = lds[t];
  if(t == 255) chunksums[blockIdx.x] = lds[255];
}

__global__ void scan2_k(int* __restrict__ chunksums, int nchunks){
  __shared__ int lds[256];
  int t = threadIdx.x;
  int x = (t < nchunks) ? chunksums[t] : 0;
  lds[t] = x; __syncthreads();
  for(int o=1;o<256;o<<=1){
    int v = (t>=o) ? lds[t-o] : 0;
    __syncthreads();
    lds[t] += v;
    __syncthreads();
  }
  if(t < nchunks) chunksums[t] = lds[t] - x;   // exclusive
}

// scan3 + dinv fused (both only need counts)
__global__ void scan3_k(const int* __restrict__ scanned, const int* __restrict__ counts,
                        const int* __restrict__ chunksums, int* __restrict__ row_start,
                        float* __restrict__ dinv, int N){
  int i = blockIdx.x*blockDim.x + threadIdx.x;
  if(i < N){
    row_start[i] = scanned[i] - counts[i] + chunksums[i>>8];
    dinv[i] = rsqrtf(1.0f + (float)counts[i]);
  }
}

// ---- CSR pass 2: atomic-free placement ----
__global__ void pass2_k(const int* __restrict__ src, const int* __restrict__ dst,
                        const int* __restrict__ rank, const int* __restrict__ row_start,
                        unsigned short* __restrict__ csr, int E){
  int e = blockIdx.x*blockDim.x + threadIdx.x;
  if(e >= E) return;
  csr[row_start[dst[e]] + rank[e]] = (unsigned short)src[e];   // N=50000 < 65536
}

// ---- W prep (bf16 swizzle, 3 layers) + graph bounds (tail threads) ----
__global__ void wprep_k(const float* __restrict__ W0, const float* __restrict__ W1,
                        const float* __restrict__ W2, unsigned short* __restrict__ Wsw,
                        const int* __restrict__ batch, int* __restrict__ bound,
                        int N, int G){
  int t = blockIdx.x*256 + threadIdx.x;
  if(t < 3*16384){
    int l = t >> 14; int i = t & 16383;
    const float* W = (l==0) ? W0 : ((l==1) ? W1 : W2);
    int k = i >> 7, n = i & 127;
    Wsw[l*16384 + (((k>>3)*128 + n)<<3) + (k&7)] = f2bf(W[k*128+n]);
  } else {
    int g = t - 3*16384;
    if(g <= G){
      int lo = 0, hi = N;
      while(lo < hi){ int mid = (lo+hi)>>1; if(batch[mid] < g) lo = mid+1; else hi = mid; }
      bound[g] = lo;
    }
  }
}

// ---- MFMA GEMM: Bh8[N,128](fp8) = dinv[row] * ( bnsig(A)[N,128] @ W[128,128] ) ----
// Layer 0: A = f32 x, no BN. Layers 1,2: A = packed-bf16 hC, BN+sigmoid fused.
__global__ __launch_bounds__(256) void gemm_mfma_k(const void* __restrict__ Avoid,
                                                   const unsigned short* __restrict__ Wsw,
                                                   unsigned char* __restrict__ Bh8,
                                                   const float* __restrict__ dinv,
                                                   const float* __restrict__ sums,
                                                   const float* __restrict__ sumsq,
                                                   const float* __restrict__ gam,
                                                   const float* __restrict__ bet,
                                                   int N){
  __shared__ unsigned short Al[16384];   // 32 KB
  __shared__ unsigned short Wl[16384];   // 32 KB
  __shared__ float scl[NDIM], shl[NDIM], dvl[NDIM];
  int t = threadIdx.x;
  int row0 = blockIdx.x * 128;
  bool bn = (sums != nullptr);

  if(bn && t < NDIM){
    float invN = 1.0f/(float)N;
    float m = sums[t]*invN;
    float var = fmaxf(sumsq[t]*invN - m*m, 0.f);
    float s = gam[t]*rsqrtf(var + 1e-5f);
    scl[t] = s; shl[t] = bet[t] - m*s;
  }
  if(t < NDIM){
    int r = row0 + t;
    dvl[t] = (r < N) ? dinv[r] : 0.f;
  }
  // stage W: 2048 x 16B coalesced copies
  #pragma unroll
  for(int i=0;i<8;i++){
    int u = t + i*256;
    *(uint4*)&Wl[u<<3] = *(const uint4*)&Wsw[u<<3];
  }
  __syncthreads();   // scl/shl ready before staging uses them

  int o = t & 15, rbase = t >> 4;
  if(bn){
    const unsigned* Ab = (const unsigned*)Avoid;   // packed bf16, N x 64 uints
    #pragma unroll
    for(int it=0; it<8; it++){
      int r = rbase + it*16;
      int grow = row0 + r;
      uint4 pk = {0,0,0,0};
      if(grow < N){
        uint4 pb = *(const uint4*)&Ab[(size_t)grow*64 + o*4];
        float a0=bflo(pb.x), a1=bfhi(pb.x), a2=bflo(pb.y), a3=bfhi(pb.y);
        float a4=bflo(pb.z), a5=bfhi(pb.z), a6=bflo(pb.w), a7=bfhi(pb.w);
        int f = o*8;
        a0 = sigmoidf_(a0*scl[f+0] + shl[f+0]);
        a1 = sigmoidf_(a1*scl[f+1] + shl[f+1]);
        a2 = sigmoidf_(a2*scl[f+2] + shl[f+2]);
        a3 = sigmoidf_(a3*scl[f+3] + shl[f+3]);
        a4 = sigmoidf_(a4*scl[f+4] + shl[f+4]);
        a5 = sigmoidf_(a5*scl[f+5] + shl[f+5]);
        a6 = sigmoidf_(a6*scl[f+6] + shl[f+6]);
        a7 = sigmoidf_(a7*scl[f+7] + shl[f+7]);
        pk.x = (unsigned)f2bf(a0) | ((unsigned)f2bf(a1)<<16);
        pk.y = (unsigned)f2bf(a2) | ((unsigned)f2bf(a3)<<16);
        pk.z = (unsigned)f2bf(a4) | ((unsigned)f2bf(a5)<<16);
        pk.w = (unsigned)f2bf(a6) | ((unsigned)f2bf(a7)<<16);
      }
      *(uint4*)&Al[(o*128 + r)<<3] = pk;
    }
  } else {
    const float* A = (const float*)Avoid;
    #pragma unroll
    for(int it=0; it<8; it++){
      int r = rbase + it*16;
      int grow = row0 + r;
      uint4 pk = {0,0,0,0};
      if(grow < N){
        float4 v0 = *(const float4*)&A[(size_t)grow*NDIM + o*8];
        float4 v1 = *(const float4*)&A[(size_t)grow*NDIM + o*8 + 4];
        pk.x = (unsigned)f2bf(v0.x) | ((unsigned)f2bf(v0.y)<<16);
        pk.y = (unsigned)f2bf(v0.z) | ((unsigned)f2bf(v0.w)<<16);
        pk.z = (unsigned)f2bf(v1.x) | ((unsigned)f2bf(v1.y)<<16);
        pk.w = (unsigned)f2bf(v1.z) | ((unsigned)f2bf(v1.w)<<16);
      }
      *(uint4*)&Al[(o*128 + r)<<3] = pk;
    }
  }
  __syncthreads();

  int wv = t >> 6, lane = t & 63, quad = lane >> 4, l16 = lane & 15;
  int rw = (wv & 1) * 64, cw = (wv >> 1) * 64;
  f32x4 acc[4][4];
  #pragma unroll
  for(int rt=0;rt<4;rt++)
    #pragma unroll
    for(int ct=0;ct<4;ct++) acc[rt][ct] = (f32x4){0.f,0.f,0.f,0.f};

  #pragma unroll
  for(int ks=0; ks<4; ks++){
    short8 a[4], b[4];
    #pragma unroll
    for(int rt=0;rt<4;rt++)
      a[rt] = *(short8*)&Al[(((ks*4+quad)*128) + rw + rt*16 + l16) << 3];
    #pragma unroll
    for(int ct=0;ct<4;ct++)
      b[ct] = *(short8*)&Wl[(((ks*4+quad)*128) + cw + ct*16 + l16) << 3];
    #pragma unroll
    for(int rt=0;rt<4;rt++)
      #pragma unroll
      for(int ct=0;ct<4;ct++)
        acc[rt][ct] = __builtin_amdgcn_mfma_f32_16x16x32_bf16(a[rt], b[ct], acc[rt][ct], 0, 0, 0);
  }

  // epilogue: C/D layout col=lane&15, row=quad*4+reg; pre-scale by dinv[row], fp8 store
  #pragma unroll
  for(int rt=0;rt<4;rt++){
    int lr = rw + rt*16 + quad*4;
    int gr = row0 + lr;
    #pragma unroll
    for(int reg=0;reg<4;reg++){
      float dv = dvl[lr + reg];
      if(gr + reg < N){
        #pragma unroll
        for(int ct=0;ct<4;ct++){
          int col = cw + ct*16 + l16;
          Bh8[(size_t)(gr+reg)*NDIM + col] = enc_fp8(acc[rt][ct][reg]*dv);
        }
      }
    }
  }
}

// ---- CSR gather aggregation: one wave per dst row; hb8 rows fp8, pre-scaled by dinv[src] ----
// hCb[i] (bf16x2) = dinv[i]*( sum_e hb8[src] + hb8[i] ) + bias
__global__ void agg_k(const unsigned short* __restrict__ hb8,   // fp8x2 per lane
                      const float* __restrict__ dinv,
                      const int* __restrict__ row_start, const int* __restrict__ counts,
                      const unsigned short* __restrict__ csr,
                      const float* __restrict__ bias, unsigned int* __restrict__ hCb, int N){
  int i = blockIdx.x;
  if(i >= N) return;
  int lane = threadIdx.x;            // 64 lanes, lane = feature pair (ushort = 2 fp8)
  int rs = row_start[i], re = rs + counts[i];
  float ax = 0.f, ay = 0.f;
  int j = rs;
  for(; j+7 < re; j += 8){           // 8 row-gathers in flight
    int s0=csr[j],   s1=csr[j+1], s2=csr[j+2], s3=csr[j+3];
    int s4=csr[j+4], s5=csr[j+5], s6=csr[j+6], s7=csr[j+7];
    unsigned u0 = hb8[(size_t)s0*64 + lane];
    unsigned u1 = hb8[(size_t)s1*64 + lane];
    unsigned u2 = hb8[(size_t)s2*64 + lane];
    unsigned u3 = hb8[(size_t)s3*64 + lane];
    unsigned u4 = hb8[(size_t)s4*64 + lane];
    unsigned u5 = hb8[(size_t)s5*64 + lane];
    unsigned u6 = hb8[(size_t)s6*64 + lane];
    unsigned u7 = hb8[(size_t)s7*64 + lane];
    ax += dec_lo(u0)+dec_lo(u1)+dec_lo(u2)+dec_lo(u3)
        + dec_lo(u4)+dec_lo(u5)+dec_lo(u6)+dec_lo(u7);
    ay += dec_hi(u0)+dec_hi(u1)+dec_hi(u2)+dec_hi(u3)
        + dec_hi(u4)+dec_hi(u5)+dec_hi(u6)+dec_hi(u7);
  }
  for(; j < re; j++){
    unsigned u0 = hb8[(size_t)csr[j]*64 + lane];
    ax += dec_lo(u0);
    ay += dec_hi(u0);
  }
  float di = dinv[i];
  unsigned su = hb8[(size_t)i*64 + lane];
  float2 bv = *(const float2*)&bias[lane*2];
  float ox = di*(ax + dec_lo(su)) + bv.x;
  float oy = di*(ay + dec_hi(su)) + bv.y;
  hCb[(size_t)i*64 + lane] = (unsigned)f2bf(ox) | ((unsigned)f2bf(oy)<<16);
}

// ---- BN column stats over packed-bf16 hC (800 blocks: 31 serial iters/thread) ----
__global__ void stats_k(const unsigned* __restrict__ hb, float* __restrict__ sums,
                        float* __restrict__ sumsq, int N){
  __shared__ float ls[256], lq[256];
  int t = threadIdx.x;
  int f = t & 127, half = t >> 7;
  int rowsPerBlock = (N + gridDim.x - 1)/gridDim.x;
  int r0 = blockIdx.x * rowsPerBlock;
  int r1 = min(N, r0 + rowsPerBlock);
  float s=0.f, q=0.f;
  for(int r=r0+half; r<r1; r+=2){
    unsigned u = hb[(size_t)r*64 + (f>>1)];
    float v = (f&1) ? bfhi(u) : bflo(u);
    s += v; q += v*v;
  }
  ls[t]=s; lq[t]=q; __syncthreads();
  if(t < 128){
    s = ls[t] + ls[t+128];
    q = lq[t] + lq[t+128];
    atomicAdd(&sums[f], s);
    atomicAdd(&sumsq[f], q);
  }
}

// ---- pooling phase 1: segment-sum of sigmoid(v*scale+shift); finalize fused ----
// PCH=32: 1563 blocks, 16 serial iters/thread (was 128/64 -- latency-bound)
#define PCH 32
__global__ __launch_bounds__(256) void pool_k(const unsigned* __restrict__ hb,
                                              const int* __restrict__ batch,
                                              const float* __restrict__ sums,
                                              const float* __restrict__ sumsq,
                                              const float* __restrict__ gam,
                                              const float* __restrict__ bet,
                                              float* __restrict__ out, int N){
  __shared__ float scl[NDIM], shl[NDIM];
  int t = threadIdx.x;
  if(t < NDIM){
    float invN = 1.0f/(float)N;
    float m = sums[t]*invN;
    float var = fmaxf(sumsq[t]*invN - m*m, 0.f);
    float s = gam[t]*rsqrtf(var + 1e-5f);
    scl[t] = s; shl[t] = bet[t] - m*s;
  }
  __syncthreads();
  int f = t & 127, half = t >> 7;
  int r0 = blockIdx.x*PCH + half;
  int r1 = min(N, blockIdx.x*PCH + PCH);
  float sc = scl[f], sh = shl[f];
  float acc = 0.f; int cur = -1;
  for(int r = r0; r < r1; r += 2){
    int g = batch[r];
    if(g != cur){
      if(cur >= 0) atomicAdd(&out[cur*NDIM + f], acc);
      acc = 0.f; cur = g;
    }
    unsigned u = hb[(size_t)r*64 + (f>>1)];
    float v = (f&1) ? bfhi(u) : bflo(u);
    acc += sigmoidf_(v*sc + sh);
  }
  if(cur >= 0) atomicAdd(&out[cur*NDIM + f], acc);
}

// ---- pooling phase 2: divide by graph size ----
__global__ void div_k(float* __restrict__ out, const int* __restrict__ bound){
  int g = blockIdx.x, f = threadIdx.x;
  float cnt = (float)(bound[g+1] - bound[g]);
  out[g*NDIM + f] /= fmaxf(cnt, 1.0f);
}

extern "C" void kernel_launch(void* const* d_in, const int* in_sizes, int n_in,
                              void* d_out, int out_size, void* d_ws, size_t ws_size,
                              hipStream_t stream){
  const float* x     = (const float*)d_in[0];
  const int*   ei    = (const int*)d_in[1];
  const int*   batch = (const int*)d_in[3];
  const float* W [3] = {(const float*)d_in[4], (const float*)d_in[6], (const float*)d_in[8]};
  const float* bi[3] = {(const float*)d_in[5], (const float*)d_in[7], (const float*)d_in[9]};
  const float* gg[3] = {(const float*)d_in[10], (const float*)d_in[12], (const float*)d_in[14]};
  const float* bb[3] = {(const float*)d_in[11], (const float*)d_in[13], (const float*)d_in[15]};

  int N = in_sizes[0] / NDIM;
  int E = in_sizes[1] / 2;
  int G = out_size / NDIM;
  const int* src = ei;
  const int* dst = ei + E;

  // workspace bump allocator (256 B aligned)
  char* p = (char*)d_ws;
  auto alloc = [&](size_t bytes)->void*{
    void* r = (void*)p; p += (bytes + 255) & ~(size_t)255; return r;
  };
  unsigned char*  hB8 = (unsigned char*) alloc((size_t)N*NDIM);     // fp8, pre-scaled by dinv
  unsigned*       hCb = (unsigned*)      alloc((size_t)N*64*4);     // packed bf16x2
  unsigned short* Wsw = (unsigned short*)alloc(3*16384*2);
  int*   counts    = (int*)  alloc((size_t)N*4);
  int*   rank      = (int*)  alloc((size_t)E*4);
  int*   scanned   = (int*)  alloc((size_t)N*4);
  int*   chunksums = (int*)  alloc(256*4);
  int*   row_start = (int*)  alloc((size_t)N*4);
  float* dinv      = (float*)alloc((size_t)N*4);
  unsigned short* csr = (unsigned short*)alloc((size_t)E*2);
  float* sums      = (float*)alloc(2*3*128*4);      // sums[3][128] + sumsq[3][128]
  float* sumsq     = sums + 3*128;
  int*   bound     = (int*)  alloc(256*4);

  hipMemsetAsync(counts, 0, (size_t)N*4, stream);
  hipMemsetAsync(sums,  0, 2*3*128*4, stream);
  hipMemsetAsync(d_out, 0, (size_t)out_size*4, stream);

  pass1_k<<<(E+255)/256, 256, 0, stream>>>(dst, counts, rank, E);

  int nchunks = (N+255)/256;     // 196 <= 256
  scan1_k<<<nchunks, 256, 0, stream>>>(counts, scanned, chunksums, N);
  scan2_k<<<1, 256, 0, stream>>>(chunksums, nchunks);
  scan3_k<<<(N+255)/256, 256, 0, stream>>>(scanned, counts, chunksums, row_start, dinv, N);
  pass2_k<<<(E+255)/256, 256, 0, stream>>>(src, dst, rank, row_start, csr, E);
  wprep_k<<<(3*16384+256+255)/256, 256, 0, stream>>>(W[0], W[1], W[2], Wsw, batch, bound, N, G);

  const void* hin = (const void*)x;
  for(int l=0; l<3; l++){
    const float* sm = (l == 0) ? nullptr : (sums  + (l-1)*128);
    const float* sq = (l == 0) ? nullptr : (sumsq + (l-1)*128);
    const float* gm = (l == 0) ? nullptr : gg[l-1];
    const float* be = (l == 0) ? nullptr : bb[l-1];
    gemm_mfma_k<<<(N+127)/128, 256, 0, stream>>>(hin, Wsw + l*16384, hB8, dinv,
                                                 sm, sq, gm, be, N);
    agg_k<<<N, 64, 0, stream>>>((const unsigned short*)hB8, dinv, row_start, counts,
                                csr, bi[l], hCb, N);
    stats_k<<<800, 256, 0, stream>>>(hCb, sums + l*128, sumsq + l*128, N);
    hin = (const void*)hCb;
  }

  pool_k<<<(N+PCH-1)/PCH, 256, 0, stream>>>(hCb, batch, sums + 2*128, sumsq + 2*128,
                                            gg[2], bb[2], (float*)d_out, N);
  div_k<<<G, 128, 0, stream>>>((float*)d_out, bound);
}